// Round 1
// 2348.133 us; speedup vs baseline: 1.0383x; 1.0383x over previous
//
#include <hip/hip_runtime.h>

// ---------- types & helpers ----------
using bf16x8 = __attribute__((ext_vector_type(8))) __bf16;
using f32x4  = __attribute__((ext_vector_type(4))) float;

#define AS1(p) ((const __attribute__((address_space(1))) void*)(p))
#define AS3(p) ((__attribute__((address_space(3))) void*)(p))

__device__ __forceinline__ unsigned short f2bf(float f) {
  unsigned u = __float_as_uint(f);
  u += 0x7fffu + ((u >> 16) & 1u);          // RNE
  return (unsigned short)(u >> 16);
}
__device__ __forceinline__ float bf2f(unsigned short h) {
  return __uint_as_float(((unsigned)h) << 16);
}

// ---------- K0a: coalesced weight transpose fp32[k][n] -> bf16[n][k] ----------
__global__ __launch_bounds__(256) void transpose_w(
    const float* __restrict__ wq, const float* __restrict__ wo,
    const float* __restrict__ w1, const float* __restrict__ w2,
    unsigned short* __restrict__ wqT, unsigned short* __restrict__ woT,
    unsigned short* __restrict__ w1T, unsigned short* __restrict__ w2T) {
  __shared__ float tile[64][65];
  const int z = blockIdx.z;
  const float* src = z == 0 ? wq : z == 1 ? wo : z == 2 ? w1 : w2;
  unsigned short* dst = z == 0 ? wqT : z == 1 ? woT : z == 2 ? w1T : w2T;
  const int tx = threadIdx.x & 63, ty = threadIdx.x >> 6;
  const int n0 = blockIdx.x * 64, k0 = blockIdx.y * 64;
#pragma unroll
  for (int i = 0; i < 16; i++) {
    int k = ty * 16 + i;
    tile[k][tx] = src[(size_t)(k0 + k) * 1024 + n0 + tx];   // coalesced read
  }
  __syncthreads();
#pragma unroll
  for (int i = 0; i < 16; i++) {
    int n = ty * 16 + i;
    dst[(size_t)(n0 + n) * 1024 + k0 + tx] = f2bf(tile[tx][n]);  // coalesced write
  }
}

// ---------- K0b: kv conversion (tiny) ----------
__global__ __launch_bounds__(256) void convert_kv(
    const float* __restrict__ kv, unsigned short* __restrict__ kvb,
    unsigned short* __restrict__ kvT) {
  int idx = blockIdx.x * 256 + threadIdx.x;       // 0..65535
  kvb[idx] = f2bf(kv[idx]);                       // [r][d]
  int h = idx >> 12, d = (idx >> 6) & 63, r = idx & 63;
  kvT[idx] = f2bf(kv[r * 1024 + h * 64 + d]);     // [h][d][r]
}

// ---------- K0c: x fp32 -> bf16 (one-shot, memory-bound) ----------
__global__ __launch_bounds__(256) void convert_x(
    const float4* __restrict__ x, ushort4* __restrict__ xb) {
  size_t i = (size_t)blockIdx.x * 256 + threadIdx.x;
  float4 v = x[i];
  ushort4 b;
  b.x = f2bf(v.x); b.y = f2bf(v.y); b.z = f2bf(v.z); b.w = f2bf(v.w);
  xb[i] = b;
}

// ---------- GEMM256: C[M,1024] = A[M,1024] @ B (B transposed [n][k] bf16) ----------
// 256x256 tile, BK=64, 8 waves (2M x 4N), per-wave 128x64 output, acc[8][4].
// Deep pipeline: double-buffered 128 KiB LDS; stage of tile t+2 issued right after
// the barrier freeing its buffer; counted s_waitcnt vmcnt(8) at iteration boundary
// (never vmcnt(0) in steady state) so next-next tile's 8 loads stay in flight
// across both barriers. Raw s_barrier + sched_barrier(0) (NOT __syncthreads, which
// would re-insert the vmcnt(0) drain).
// LDS swizzle: logical (row r, 16B-chunk c) -> physical slot r*8 + (c ^ (r&7));
// applied as pre-swizzled global source (global_load_lds dest stays linear) and
// XOR'd ds_read address. Makes stride-128B fragment reads 2-way (free).
// EPI 0: store bf16 * scale   EPI 1: gelu(acc + bias)   EPI 2: +bias+resid, mean-pool
template <int EPI>
__global__ __launch_bounds__(512, 2) void gemm256(
    const unsigned short* __restrict__ A, const unsigned short* __restrict__ BT,
    unsigned short* __restrict__ C, const float* __restrict__ bias,
    const unsigned short* __restrict__ resid, float* __restrict__ pool,
    float scale) {
  __shared__ unsigned short Asm[2 * 16384];   // 2 buffers x 256 rows x 64 bf16
  __shared__ unsigned short Bsm[2 * 16384];
  const int tid = threadIdx.x;
  const int lane = tid & 63, wave = tid >> 6;
  const int wr = wave >> 2, wc = wave & 3;    // 2 x 4 wave grid
  const int l15 = lane & 15, l4 = lane >> 4;

  // XCD-bijective swizzle: 2048 blocks, each XCD gets 64 contiguous row-panels
  // x 4 col tiles; consecutive blocks on an XCD share the A row-panel (L2 reuse),
  // B (2 MB) resides fully in each XCD's L2.
  const int bid = blockIdx.x;
  const int idx = bid >> 3;
  const int row0 = ((bid & 7) * 64 + (idx >> 2)) * 256;
  const int col0 = (idx & 3) * 256;

  // per-thread staging slots: slot p = tid + 512*s; r = p>>3; chunk = (p&7)^(r&7)
  const unsigned short* aSrc[4];
  const unsigned short* bSrc[4];
#pragma unroll
  for (int s = 0; s < 4; s++) {
    int p = tid + 512 * s;
    int r = p >> 3, c = (p & 7) ^ (r & 7);
    aSrc[s] = A  + (size_t)(row0 + r) * 1024 + c * 8;
    bSrc[s] = BT + (size_t)(col0 + r) * 1024 + c * 8;
  }

  auto stage = [&](int t, int b) {
#pragma unroll
    for (int s = 0; s < 4; s++)
      __builtin_amdgcn_global_load_lds(AS1(aSrc[s] + t * 64),
                                       AS3(Asm + b * 16384 + (tid + 512 * s) * 8), 16, 0, 0);
#pragma unroll
    for (int s = 0; s < 4; s++)
      __builtin_amdgcn_global_load_lds(AS1(bSrc[s] + t * 64),
                                       AS3(Bsm + b * 16384 + (tid + 512 * s) * 8), 16, 0, 0);
  };

  f32x4 acc[8][4];
#pragma unroll
  for (int i = 0; i < 8; i++)
#pragma unroll
    for (int j = 0; j < 4; j++) acc[i][j] = f32x4{0.f, 0.f, 0.f, 0.f};

  // precomputed swizzled LDS element offsets (ks=0; ks=1 is ^32)
  int aOff[8], bOff[4];
#pragma unroll
  for (int i = 0; i < 8; i++) {
    int ra = wr * 128 + i * 16 + l15;
    aOff[i] = ra * 64 + ((l4 ^ (ra & 7)) * 8);
  }
#pragma unroll
  for (int j = 0; j < 4; j++) {
    int rb = wc * 64 + j * 16 + l15;
    bOff[j] = rb * 64 + ((l4 ^ (rb & 7)) * 8);
  }

  auto compute = [&](int b) {
#pragma unroll
    for (int ks = 0; ks < 2; ks++) {
      bf16x8 af[8], bfr[4];
#pragma unroll
      for (int i = 0; i < 8; i++)
        af[i] = *(const bf16x8*)(Asm + b * 16384 + (aOff[i] ^ (ks * 32)));
#pragma unroll
      for (int j = 0; j < 4; j++)
        bfr[j] = *(const bf16x8*)(Bsm + b * 16384 + (bOff[j] ^ (ks * 32)));
      __builtin_amdgcn_s_setprio(1);
#pragma unroll
      for (int i = 0; i < 8; i++)
#pragma unroll
        for (int j = 0; j < 4; j++)
          acc[i][j] = __builtin_amdgcn_mfma_f32_16x16x32_bf16(af[i], bfr[j], acc[i][j], 0, 0, 0);
      __builtin_amdgcn_s_setprio(0);
    }
  };

  // prologue: tiles 0,1 staged; wait tile 0 (own 8 newest outstanding = tile 1)
  stage(0, 0);
  stage(1, 1);
  asm volatile("s_waitcnt vmcnt(8)" ::: "memory");
  __builtin_amdgcn_sched_barrier(0);
  __builtin_amdgcn_s_barrier();
  __builtin_amdgcn_sched_barrier(0);

  int cur = 0;
#pragma unroll 2
  for (int t = 0; t < 14; ++t) {
    compute(cur);
    // barrier A: all waves' reads of buf[cur] complete -> safe to overwrite
    __builtin_amdgcn_sched_barrier(0);
    __builtin_amdgcn_s_barrier();
    __builtin_amdgcn_sched_barrier(0);
    stage(t + 2, cur);
    // counted wait: 8 newest (tile t+2) stay in flight; tile t+1 has landed
    asm volatile("s_waitcnt vmcnt(8)" ::: "memory");
    __builtin_amdgcn_sched_barrier(0);
    __builtin_amdgcn_s_barrier();   // barrier B: t+1 visible to all waves
    __builtin_amdgcn_sched_barrier(0);
    cur ^= 1;
  }
  compute(cur);                                   // t=14 (buf0)
  asm volatile("s_waitcnt vmcnt(0)" ::: "memory");// drain tile 15's loads
  __builtin_amdgcn_sched_barrier(0);
  __builtin_amdgcn_s_barrier();
  __builtin_amdgcn_sched_barrier(0);
  compute(cur ^ 1);                               // t=15 (buf1)

  if (EPI == 0) {
#pragma unroll
    for (int i = 0; i < 8; i++)
#pragma unroll
      for (int j = 0; j < 4; j++)
#pragma unroll
        for (int v = 0; v < 4; v++) {
          int row = row0 + wr * 128 + i * 16 + l4 * 4 + v;
          int col = col0 + wc * 64 + j * 16 + l15;
          C[(size_t)row * 1024 + col] = f2bf(acc[i][j][v] * scale);
        }
  } else if (EPI == 1) {
#pragma unroll
    for (int j = 0; j < 4; j++) {
      int col = col0 + wc * 64 + j * 16 + l15;
      float bj = bias[col];
#pragma unroll
      for (int i = 0; i < 8; i++)
#pragma unroll
        for (int v = 0; v < 4; v++) {
          int row = row0 + wr * 128 + i * 16 + l4 * 4 + v;
          float val = acc[i][j][v] + bj;
          float g = 0.5f * val * (1.0f + erff(val * 0.70710678118654752f));
          C[(size_t)row * 1024 + col] = f2bf(g);
        }
    }
  } else {  // EPI == 2: residual + bias + mean-pool
    float cs[4] = {0.f, 0.f, 0.f, 0.f};
#pragma unroll
    for (int j = 0; j < 4; j++) {
      int col = col0 + wc * 64 + j * 16 + l15;
      float bj = bias[col];
#pragma unroll
      for (int i = 0; i < 8; i++)
#pragma unroll
        for (int v = 0; v < 4; v++) {
          int row = row0 + wr * 128 + i * 16 + l4 * 4 + v;
          float val = acc[i][j][v] + bj + bf2f(resid[(size_t)row * 1024 + col]);
          cs[j] += val;
        }
    }
#pragma unroll
    for (int j = 0; j < 4; j++) {
      cs[j] += __shfl_xor(cs[j], 16);
      cs[j] += __shfl_xor(cs[j], 32);
    }
    if (l4 == 0) {
      int b = row0 >> 12;  // 4096 tokens per batch; 256-row tiles never straddle
#pragma unroll
      for (int j = 0; j < 4; j++) {
        int col = col0 + wc * 64 + j * 16 + l15;
        atomicAdd(pool + b * 1024 + col, cs[j] * (1.0f / 4096.0f));
      }
    }
  }
}

// ---------- K2: latent attention (128 tokens x 2 heads per block) ----------
__global__ __launch_bounds__(256) void attn_kernel(
    const unsigned short* __restrict__ q, const unsigned short* __restrict__ kvb,
    const unsigned short* __restrict__ kvT, unsigned short* __restrict__ outp) {
  __shared__ unsigned short smem[32768];  // 64 KB
  unsigned short* qs   = smem;            // [128][128]  (aliased by attn later)
  unsigned short* kvs  = smem + 16384;    // [2][64 r][64 d]
  unsigned short* kvTs = smem + 24576;    // [2][64 d][64 r]
  const int tid = threadIdx.x;
  const int lane = tid & 63, wave = tid >> 6;
  const int wr = wave >> 1, wc = wave & 1;
  const int l15 = lane & 15, l4 = lane >> 4;
  const int hp = blockIdx.x, row0 = blockIdx.y * 128;

#pragma unroll
  for (int t = 0; t < 8; t++) {           // q tile: 2048 x 16B
    int c = wave * 512 + t * 64 + lane;
    int r = c >> 4, c8 = c & 15;
    __builtin_amdgcn_global_load_lds(AS1(q + (size_t)(row0 + r) * 1024 + hp * 128 + c8 * 8),
                                     AS3(qs + (wave * 512 + t * 64) * 8), 16, 0, 0);
  }
#pragma unroll
  for (int t = 0; t < 4; t++) {           // kv + kvT: 1024 x 16B each
    int c = wave * 256 + t * 64 + lane;
    int h = c >> 9, r = (c >> 3) & 63, c8 = c & 7;
    __builtin_amdgcn_global_load_lds(AS1(kvb + r * 1024 + (hp * 2 + h) * 64 + c8 * 8),
                                     AS3(kvs + (wave * 256 + t * 64) * 8), 16, 0, 0);
    __builtin_amdgcn_global_load_lds(AS1(kvT + (hp * 2 + h) * 4096 + (c & 511) * 8),
                                     AS3(kvTs + (wave * 256 + t * 64) * 8), 16, 0, 0);
  }
  __syncthreads();

  // scores[row][r] for head wc, rows wr*64..+63
  f32x4 sc[4][4];
#pragma unroll
  for (int i = 0; i < 4; i++)
#pragma unroll
    for (int j = 0; j < 4; j++) sc[i][j] = f32x4{0.f, 0.f, 0.f, 0.f};
#pragma unroll
  for (int ks = 0; ks < 2; ks++) {
    bf16x8 af[4], bfr[4];
#pragma unroll
    for (int i = 0; i < 4; i++)
      af[i] = *(const bf16x8*)(qs + (wr * 64 + i * 16 + l15) * 128 + wc * 64 + ks * 32 + l4 * 8);
#pragma unroll
    for (int j = 0; j < 4; j++)
      bfr[j] = *(const bf16x8*)(kvs + wc * 4096 + (j * 16 + l15) * 64 + ks * 32 + l4 * 8);
#pragma unroll
    for (int i = 0; i < 4; i++)
#pragma unroll
      for (int j = 0; j < 4; j++)
        sc[i][j] = __builtin_amdgcn_mfma_f32_16x16x32_bf16(af[i], bfr[j], sc[i][j], 0, 0, 0);
  }
  __syncthreads();  // all qs reads done; attn aliases qs

  unsigned short* attn = qs;  // [2][128][64], wave-private regions
#pragma unroll
  for (int i = 0; i < 4; i++)
#pragma unroll
    for (int v = 0; v < 4; v++) {
      float m = fmaxf(fmaxf(sc[i][0][v], sc[i][1][v]), fmaxf(sc[i][2][v], sc[i][3][v]));
#pragma unroll
      for (int msk = 1; msk <= 8; msk <<= 1) m = fmaxf(m, __shfl_xor(m, msk));
      float e0 = __expf(sc[i][0][v] - m), e1 = __expf(sc[i][1][v] - m);
      float e2 = __expf(sc[i][2][v] - m), e3 = __expf(sc[i][3][v] - m);
      float s = e0 + e1 + e2 + e3;
#pragma unroll
      for (int msk = 1; msk <= 8; msk <<= 1) s += __shfl_xor(s, msk);
      float inv = 1.0f / s;
      int row = wr * 64 + i * 16 + l4 * 4 + v;
      attn[wc * 8192 + row * 64 + 0 * 16 + l15] = f2bf(e0 * inv);
      attn[wc * 8192 + row * 64 + 1 * 16 + l15] = f2bf(e1 * inv);
      attn[wc * 8192 + row * 64 + 2 * 16 + l15] = f2bf(e2 * inv);
      attn[wc * 8192 + row * 64 + 3 * 16 + l15] = f2bf(e3 * inv);
    }

  // out[row][d] = attn @ kv   (B = kvT[d][r])
  f32x4 o[4][4];
#pragma unroll
  for (int i = 0; i < 4; i++)
#pragma unroll
    for (int j = 0; j < 4; j++) o[i][j] = f32x4{0.f, 0.f, 0.f, 0.f};
#pragma unroll
  for (int ks = 0; ks < 2; ks++) {
    bf16x8 af[4], bfr[4];
#pragma unroll
    for (int i = 0; i < 4; i++)
      af[i] = *(const bf16x8*)(attn + wc * 8192 + (wr * 64 + i * 16 + l15) * 64 + ks * 32 + l4 * 8);
#pragma unroll
    for (int j = 0; j < 4; j++)
      bfr[j] = *(const bf16x8*)(kvTs + wc * 4096 + (j * 16 + l15) * 64 + ks * 32 + l4 * 8);
#pragma unroll
    for (int i = 0; i < 4; i++)
#pragma unroll
      for (int j = 0; j < 4; j++)
        o[i][j] = __builtin_amdgcn_mfma_f32_16x16x32_bf16(af[i], bfr[j], o[i][j], 0, 0, 0);
  }
#pragma unroll
  for (int i = 0; i < 4; i++)
#pragma unroll
    for (int j = 0; j < 4; j++)
#pragma unroll
      for (int v = 0; v < 4; v++) {
        int row = row0 + wr * 64 + i * 16 + l4 * 4 + v;
        int col = (hp * 2 + wc) * 64 + j * 16 + l15;
        outp[(size_t)row * 1024 + col] = f2bf(o[i][j][v]);
      }
}

// ---------- launch ----------
extern "C" void kernel_launch(void* const* d_in, const int* in_sizes, int n_in,
                              void* d_out, int out_size, void* d_ws, size_t ws_size,
                              hipStream_t stream) {
  const float* x  = (const float*)d_in[0];
  const float* wq = (const float*)d_in[1];
  const float* kv = (const float*)d_in[2];
  const float* wo = (const float*)d_in[3];
  const float* w1 = (const float*)d_in[4];
  const float* b1 = (const float*)d_in[5];
  const float* w2 = (const float*)d_in[6];
  const float* b2 = (const float*)d_in[7];
  char* ws = (char*)d_ws;
  const size_t MB = 1024 * 1024;
  unsigned short* wqT = (unsigned short*)(ws + 0 * MB);
  unsigned short* woT = (unsigned short*)(ws + 2 * MB);
  unsigned short* w1T = (unsigned short*)(ws + 4 * MB);
  unsigned short* w2T = (unsigned short*)(ws + 6 * MB);
  unsigned short* kvb = (unsigned short*)(ws + 8 * MB);
  unsigned short* kvT = (unsigned short*)(ws + 8 * MB + 256 * 1024);
  unsigned short* buf1 = (unsigned short*)(ws + 16 * MB);             // q, then y
  unsigned short* buf2 = (unsigned short*)(ws + 16 * MB + 256 * MB);  // xb, attn_out, h
  float* out = (float*)d_out;

  hipMemsetAsync(d_out, 0, (size_t)out_size * sizeof(float), stream);
  transpose_w<<<dim3(16, 16, 4), 256, 0, stream>>>(wq, wo, w1, w2, wqT, woT, w1T, w2T);
  convert_kv<<<256, 256, 0, stream>>>(kv, kvb, kvT);
  // K0c: xb = bf16(x) into buf2 (x not needed afterwards; attn overwrites buf2)
  convert_x<<<131072, 256, 0, stream>>>((const float4*)x, (ushort4*)buf2);

  // K1: q = (xb @ wq) * R^-0.5
  gemm256<0><<<2048, 512, 0, stream>>>(buf2, wqT, buf1, nullptr, nullptr, nullptr, 0.125f);
  // K2: latent attention
  attn_kernel<<<dim3(8, 1024), 256, 0, stream>>>(buf1, kvb, kvT, buf2);
  // K3: y = attn_out @ wo
  gemm256<0><<<2048, 512, 0, stream>>>(buf2, woT, buf1, nullptr, nullptr, nullptr, 1.0f);
  // K4: h = gelu(y @ w1 + b1)
  gemm256<1><<<2048, 512, 0, stream>>>(buf1, w1T, buf2, b1, nullptr, nullptr, 1.0f);
  // K5: out_final = h @ w2 + b2 + y  -> mean-pool into d_out
  gemm256<2><<<2048, 512, 0, stream>>>(buf2, w2T, nullptr, b2, buf1, out, 1.0f);
}